// Round 1
// baseline (66.836 us; speedup 1.0000x reference)
//
#include <hip/hip_runtime.h>

// Problem constants (from the JAX reference)
constexpr int B = 4;
constexpr int L = 4096;
constexpr int D = 2048;
constexpr int K = 4;
constexpr float EPS = 1e-5f;

constexpr int CL = 64;   // L-chunk per block in the conv kernel

// ---------------------------------------------------------------------------
// Kernel 1: inv_rms[row] = rsqrt(mean(x[row,:]^2) + eps) for row in [0, B*L)
// 256 threads/block, one block per row; each thread reads 8 contiguous floats.
// ---------------------------------------------------------------------------
__global__ __launch_bounds__(256) void rms_kernel(const float* __restrict__ x,
                                                  float* __restrict__ inv_rms) {
    const int row = blockIdx.x;                 // [0, B*L)
    const float* xr = x + (size_t)row * D;
    const int t = threadIdx.x;                  // 0..255

    const float4* xr4 = reinterpret_cast<const float4*>(xr);
    float4 a = xr4[2 * t];
    float4 b = xr4[2 * t + 1];
    float s = a.x * a.x + a.y * a.y + a.z * a.z + a.w * a.w
            + b.x * b.x + b.y * b.y + b.z * b.z + b.w * b.w;

    // wave (64-lane) reduction
    #pragma unroll
    for (int off = 32; off > 0; off >>= 1)
        s += __shfl_down(s, off, 64);

    __shared__ float wsum[4];
    const int wave = t >> 6;
    if ((t & 63) == 0) wsum[wave] = s;
    __syncthreads();

    if (t == 0) {
        float tot = wsum[0] + wsum[1] + wsum[2] + wsum[3];
        inv_rms[row] = rsqrtf(tot * (1.0f / D) + EPS);
    }
}

// ---------------------------------------------------------------------------
// Kernel 2: fused (normalize -> causal depthwise conv K=4 -> SiLU)
// Each thread owns 4 consecutive channels (float4) and slides over CL rows,
// keeping the last 3 normalized values in registers (x read once).
// Block: 512 threads covering all D/4 = 512 float4 channel groups.
// Grid: (L/CL, B)
// ---------------------------------------------------------------------------
__device__ __forceinline__ void load4(const float* p, float r[4]) {
    float4 v = *reinterpret_cast<const float4*>(p);
    r[0] = v.x; r[1] = v.y; r[2] = v.z; r[3] = v.w;
}

__global__ __launch_bounds__(512) void conv_kernel(const float* __restrict__ x,
                                                   const float* __restrict__ nw,
                                                   const float* __restrict__ cw,
                                                   const float* __restrict__ inv_rms,
                                                   float* __restrict__ out) {
    const int t = threadIdx.x;          // 0..511 -> dvec index
    const int chunk = blockIdx.x;       // 0..L/CL-1
    const int b = blockIdx.y;           // 0..B-1
    const int l0 = chunk * CL;
    const int d = t * 4;

    const float* xb = x + (size_t)b * L * D;
    float* ob = out + (size_t)b * L * D;
    const float* ir = inv_rms + (size_t)b * L;

    // Stage inv_rms for rows [l0-3, l0+CL) in LDS
    __shared__ float s_ir[CL + 3];
    if (t < CL + 3) {
        int l = l0 - 3 + t;
        s_ir[t] = (l >= 0) ? ir[l] : 0.0f;
    }
    __syncthreads();

    float nwv[4], w0v[4], w1v[4], w2v[4], w3v[4];
    load4(nw + d, nwv);
    load4(cw + 0 * D + d, w0v);   // conv_weight is (K, 1, D): [k*D + d]
    load4(cw + 1 * D + d, w1v);
    load4(cw + 2 * D + d, w2v);
    load4(cw + 3 * D + d, w3v);

    // Sliding window of normalized x: win[0]=l-3, win[1]=l-2, win[2]=l-1
    float win[3][4] = {};
    #pragma unroll
    for (int j = 0; j < 3; ++j) {
        int l = l0 - 3 + j;
        if (l >= 0) {
            float xv[4];
            load4(xb + (size_t)l * D + d, xv);
            float s = s_ir[j];
            #pragma unroll
            for (int i = 0; i < 4; ++i) win[j][i] = xv[i] * s * nwv[i];
        }
    }

    for (int li = 0; li < CL; ++li) {
        const int l = l0 + li;
        float xv[4];
        load4(xb + (size_t)l * D + d, xv);
        const float s = s_ir[3 + li];

        float cur[4], y[4];
        #pragma unroll
        for (int i = 0; i < 4; ++i) {
            cur[i] = xv[i] * s * nwv[i];
            y[i] = w0v[i] * win[0][i] + w1v[i] * win[1][i]
                 + w2v[i] * win[2][i] + w3v[i] * cur[i];
            float sg = 1.0f / (1.0f + __expf(-y[i]));
            y[i] *= sg;
        }

        float4 o = make_float4(y[0], y[1], y[2], y[3]);
        *reinterpret_cast<float4*>(ob + (size_t)l * D + d) = o;

        #pragma unroll
        for (int i = 0; i < 4; ++i) {
            win[0][i] = win[1][i];
            win[1][i] = win[2][i];
            win[2][i] = cur[i];
        }
    }
}

extern "C" void kernel_launch(void* const* d_in, const int* in_sizes, int n_in,
                              void* d_out, int out_size, void* d_ws, size_t ws_size,
                              hipStream_t stream) {
    const float* x  = (const float*)d_in[0];   // (B, L, D) fp32
    const float* nw = (const float*)d_in[1];   // (D,) fp32
    const float* cw = (const float*)d_in[2];   // (K, 1, D) fp32
    float* out = (float*)d_out;                // (B, L, D) fp32
    float* inv_rms = (float*)d_ws;             // B*L floats = 64 KB scratch

    rms_kernel<<<B * L, 256, 0, stream>>>(x, inv_rms);
    conv_kernel<<<dim3(L / CL, B), 512, 0, stream>>>(x, nw, cw, inv_rms, out);
}

// Round 2
// 51.520 us; speedup vs baseline: 1.2973x; 1.2973x over previous
//
#include <hip/hip_runtime.h>

// Problem constants (from the JAX reference)
constexpr int B = 4;
constexpr int L = 4096;
constexpr int D = 2048;
constexpr int K = 4;
constexpr float EPS = 1e-5f;

constexpr int CL = 16;    // L-rows per block
constexpr int NW = 8;     // waves per block (512 threads)

__device__ __forceinline__ void load4(const float* p, float r[4]) {
    float4 v = *reinterpret_cast<const float4*>(p);
    r[0] = v.x; r[1] = v.y; r[2] = v.z; r[3] = v.w;
}

// Block-wide sum of per-thread s -> inv_rms. One __syncthreads per call;
// `slot` must alternate between two LDS buffers across consecutive calls.
__device__ __forceinline__ float row_invrms(float s, float* slot, int wave, int lane) {
    #pragma unroll
    for (int off = 32; off > 0; off >>= 1)
        s += __shfl_down(s, off, 64);
    if (lane == 0) slot[wave] = s;
    __syncthreads();
    float tot = 0.0f;
    #pragma unroll
    for (int w = 0; w < NW; ++w) tot += slot[w];
    return rsqrtf(tot * (1.0f / D) + EPS);
}

// ---------------------------------------------------------------------------
// Fully fused: RMSNorm -> causal depthwise conv (K=4) -> SiLU, single pass.
// Block covers all of D (512 threads x float4) for CL consecutive rows.
// x is read once (plus 3 halo rows per block, L3-absorbed).
// ---------------------------------------------------------------------------
__global__ __launch_bounds__(512) void fused_kernel(const float* __restrict__ x,
                                                    const float* __restrict__ nw,
                                                    const float* __restrict__ cw,
                                                    float* __restrict__ out) {
    const int t = threadIdx.x;          // 0..511
    const int wave = t >> 6;
    const int lane = t & 63;
    const int chunk = blockIdx.x;       // 0..L/CL-1
    const int b = blockIdx.y;           // 0..B-1
    const int l0 = chunk * CL;
    const int d = t * 4;

    const float* xb = x + (size_t)b * L * D;
    float* ob = out + (size_t)b * L * D;

    __shared__ float s_red[2][NW];
    int par = 0;                        // reduction slot parity

    float nwv[4], w0v[4], w1v[4], w2v[4], w3v[4];
    load4(nw + d, nwv);
    load4(cw + 0 * D + d, w0v);         // conv_weight is (K, 1, D): [k*D + d]
    load4(cw + 1 * D + d, w1v);
    load4(cw + 2 * D + d, w2v);
    load4(cw + 3 * D + d, w3v);

    // --- Halo: recompute normalized rows l0-3 .. l0-1 into the window ---
    float win[3][4];
    #pragma unroll
    for (int j = 0; j < 3; ++j) {
        const int l = l0 - 3 + j;
        float xv[4] = {0.f, 0.f, 0.f, 0.f};
        if (l >= 0) load4(xb + (size_t)l * D + d, xv);
        float s = xv[0]*xv[0] + xv[1]*xv[1] + xv[2]*xv[2] + xv[3]*xv[3];
        float irms = row_invrms(s, s_red[par], wave, lane);
        par ^= 1;
        #pragma unroll
        for (int i = 0; i < 4; ++i) win[j][i] = xv[i] * irms * nwv[i];
    }

    // --- Main loop over CL rows with one-row prefetch ---
    float xnext[4];
    load4(xb + (size_t)l0 * D + d, xnext);

    for (int li = 0; li < CL; ++li) {
        float xv[4];
        #pragma unroll
        for (int i = 0; i < 4; ++i) xv[i] = xnext[i];
        if (li + 1 < CL)
            load4(xb + (size_t)(l0 + li + 1) * D + d, xnext);

        float s = xv[0]*xv[0] + xv[1]*xv[1] + xv[2]*xv[2] + xv[3]*xv[3];
        float irms = row_invrms(s, s_red[par], wave, lane);
        par ^= 1;

        float cur[4], y[4];
        #pragma unroll
        for (int i = 0; i < 4; ++i) {
            cur[i] = xv[i] * irms * nwv[i];
            y[i] = w0v[i] * win[0][i] + w1v[i] * win[1][i]
                 + w2v[i] * win[2][i] + w3v[i] * cur[i];
            float sg = 1.0f / (1.0f + __expf(-y[i]));
            y[i] *= sg;
        }

        *reinterpret_cast<float4*>(ob + (size_t)(l0 + li) * D + d) =
            make_float4(y[0], y[1], y[2], y[3]);

        #pragma unroll
        for (int i = 0; i < 4; ++i) {
            win[0][i] = win[1][i];
            win[1][i] = win[2][i];
            win[2][i] = cur[i];
        }
    }
}

extern "C" void kernel_launch(void* const* d_in, const int* in_sizes, int n_in,
                              void* d_out, int out_size, void* d_ws, size_t ws_size,
                              hipStream_t stream) {
    const float* x  = (const float*)d_in[0];   // (B, L, D) fp32
    const float* nw = (const float*)d_in[1];   // (D,) fp32
    const float* cw = (const float*)d_in[2];   // (K, 1, D) fp32
    float* out = (float*)d_out;                // (B, L, D) fp32

    fused_kernel<<<dim3(L / CL, B), 512, 0, stream>>>(x, nw, cw, out);
}

// Round 4
// 50.506 us; speedup vs baseline: 1.3233x; 1.0201x over previous
//
#include <hip/hip_runtime.h>

// Problem constants (from the JAX reference)
constexpr int B = 4;
constexpr int L = 4096;
constexpr int D = 2048;
constexpr float EPS = 1e-5f;

constexpr int CL = 16;   // L-rows per block
constexpr int R  = 4;    // rows per barrier group
constexpr int NG = CL / R;
constexpr int NW = 8;    // waves per block (512 threads)

typedef float floatx4 __attribute__((ext_vector_type(4)));

__device__ __forceinline__ void load4(const float* __restrict__ p, float r[4]) {
    floatx4 v = *reinterpret_cast<const floatx4*>(p);
    r[0] = v.x; r[1] = v.y; r[2] = v.z; r[3] = v.w;
}

// ---------------------------------------------------------------------------
// Fully fused: RMSNorm -> causal depthwise conv (K=4) -> SiLU, single pass.
// Block covers all of D (512 threads x float4) for CL consecutive rows.
// R=4 rows share one barrier (batched block reduction, double-buffered LDS).
// ---------------------------------------------------------------------------
__global__ __launch_bounds__(512) void fused_kernel(const float* __restrict__ x,
                                                    const float* __restrict__ nw,
                                                    const float* __restrict__ cw,
                                                    float* __restrict__ out) {
    const int t = threadIdx.x;          // 0..511
    const int wave = t >> 6;
    const int lane = t & 63;
    const int l0 = blockIdx.x * CL;
    const int b = blockIdx.y;
    const int d = t * 4;

    const float* xb = x + (size_t)b * L * D + d;
    float* ob = out + (size_t)b * L * D + d;

    __shared__ float s_red[2][R][NW];

    float nwv[4], wv[4][4];
    load4(nw + d, nwv);
    #pragma unroll
    for (int k = 0; k < 4; ++k) load4(cw + k * D + d, wv[k]);  // (K,1,D)

    // ---- Halo: rows l0-3 .. l0-1, batched: 3 reduces, ONE barrier ----
    float win[3][4];
    {
        float hx[3][4];
        #pragma unroll
        for (int j = 0; j < 3; ++j) {
            const int l = l0 - 3 + j;
            hx[j][0] = hx[j][1] = hx[j][2] = hx[j][3] = 0.0f;
            if (l >= 0) load4(xb + (size_t)l * D, hx[j]);
            float s = hx[j][0]*hx[j][0] + hx[j][1]*hx[j][1]
                    + hx[j][2]*hx[j][2] + hx[j][3]*hx[j][3];
            #pragma unroll
            for (int off = 32; off > 0; off >>= 1)
                s += __shfl_down(s, off, 64);
            if (lane == 0) s_red[0][j][wave] = s;
        }
        __syncthreads();
        #pragma unroll
        for (int j = 0; j < 3; ++j) {
            float tot = 0.0f;
            #pragma unroll
            for (int w = 0; w < NW; ++w) tot += s_red[0][j][w];
            float irms = rsqrtf(tot * (1.0f / D) + EPS);
            #pragma unroll
            for (int i = 0; i < 4; ++i) win[j][i] = hx[j][i] * irms * nwv[i];
        }
    }

    // ---- Main: NG groups of R rows, one barrier per group ----
    float cur[R][4], nxt[R][4];
    #pragma unroll
    for (int r = 0; r < R; ++r)
        load4(xb + (size_t)(l0 + r) * D, cur[r]);

    #pragma unroll
    for (int g = 0; g < NG; ++g) {
        const int par = (g + 1) & 1;    // halo used buffer 0

        // 4 independent reduce chains
        #pragma unroll
        for (int r = 0; r < R; ++r) {
            float s = cur[r][0]*cur[r][0] + cur[r][1]*cur[r][1]
                    + cur[r][2]*cur[r][2] + cur[r][3]*cur[r][3];
            #pragma unroll
            for (int off = 32; off > 0; off >>= 1)
                s += __shfl_down(s, off, 64);
            if (lane == 0) s_red[par][r][wave] = s;
        }

        // prefetch next group's rows before the barrier drain
        if (g + 1 < NG) {
            #pragma unroll
            for (int r = 0; r < R; ++r)
                load4(xb + (size_t)(l0 + (g + 1) * R + r) * D, nxt[r]);
        }

        __syncthreads();

        #pragma unroll
        for (int r = 0; r < R; ++r) {
            float tot = 0.0f;
            #pragma unroll
            for (int w = 0; w < NW; ++w) tot += s_red[par][r][w];
            const float irms = rsqrtf(tot * (1.0f / D) + EPS);

            float c[4], y[4];
            #pragma unroll
            for (int i = 0; i < 4; ++i) {
                c[i] = cur[r][i] * irms * nwv[i];
                y[i] = wv[0][i]*win[0][i] + wv[1][i]*win[1][i]
                     + wv[2][i]*win[2][i] + wv[3][i]*c[i];
                y[i] = y[i] / (1.0f + __expf(-y[i]));   // SiLU
            }
            floatx4 o;
            o.x = y[0]; o.y = y[1]; o.z = y[2]; o.w = y[3];
            __builtin_nontemporal_store(o,
                reinterpret_cast<floatx4*>(ob + (size_t)(l0 + g * R + r) * D));

            #pragma unroll
            for (int i = 0; i < 4; ++i) {
                win[0][i] = win[1][i];
                win[1][i] = win[2][i];
                win[2][i] = c[i];
            }
        }

        #pragma unroll
        for (int r = 0; r < R; ++r)
            #pragma unroll
            for (int i = 0; i < 4; ++i) cur[r][i] = nxt[r][i];
    }
}

extern "C" void kernel_launch(void* const* d_in, const int* in_sizes, int n_in,
                              void* d_out, int out_size, void* d_ws, size_t ws_size,
                              hipStream_t stream) {
    const float* x  = (const float*)d_in[0];   // (B, L, D) fp32
    const float* nw = (const float*)d_in[1];   // (D,) fp32
    const float* cw = (const float*)d_in[2];   // (K, 1, D) fp32
    float* out = (float*)d_out;                // (B, L, D) fp32

    fused_kernel<<<dim3(L / CL, B), 512, 0, stream>>>(x, nw, cw, out);
}

// Round 5
// 48.973 us; speedup vs baseline: 1.3648x; 1.0313x over previous
//
#include <hip/hip_runtime.h>

// Problem constants (from the JAX reference)
constexpr int B = 4;
constexpr int L = 4096;
constexpr int D = 2048;
constexpr float EPS = 1e-5f;

constexpr int CL = 16;         // L-rows per block
constexpr int R  = 4;          // rows per barrier group
constexpr int NG = CL / R;
constexpr int NW = 8;          // waves per block (512 threads)
constexpr int NCHUNK = L / CL; // 256
constexpr int NWG = NCHUNK * B;// 1024 blocks (divisible by 8 XCDs)

typedef float floatx4 __attribute__((ext_vector_type(4)));

__device__ __forceinline__ void load4(const float* __restrict__ p, float r[4]) {
    floatx4 v = *reinterpret_cast<const floatx4*>(p);
    r[0] = v.x; r[1] = v.y; r[2] = v.z; r[3] = v.w;
}

// Barrier that only drains LDS ops (lgkmcnt), NOT outstanding global loads
// (vmcnt). The prefetched next-group loads stay in flight across it; the
// compiler still inserts vmcnt waits at their point of consumption.
__device__ __forceinline__ void light_barrier() {
    asm volatile("s_waitcnt lgkmcnt(0)" ::: "memory");
    __builtin_amdgcn_s_barrier();
    asm volatile("" ::: "memory");
}

// ---------------------------------------------------------------------------
// Fully fused: RMSNorm -> causal depthwise conv (K=4) -> SiLU, single pass.
// Block covers all of D (512 threads x float4) for CL consecutive rows.
// R=4 rows share one barrier (batched block reduction, double-buffered LDS).
// ---------------------------------------------------------------------------
__global__ __launch_bounds__(512) void fused_kernel(const float* __restrict__ x,
                                                    const float* __restrict__ nw,
                                                    const float* __restrict__ cw,
                                                    float* __restrict__ out) {
    const int t = threadIdx.x;          // 0..511
    const int wave = t >> 6;
    const int lane = t & 63;

    // XCD-aware swizzle: consecutive work ids (adjacent L-chunks, sharing
    // halo rows) land on the same XCD's L2. NWG % 8 == 0 -> bijective.
    const int bid = blockIdx.x;
    const int swz = (bid & 7) * (NWG / 8) + (bid >> 3);
    const int b = swz / NCHUNK;
    const int chunk = swz % NCHUNK;
    const int l0 = chunk * CL;
    const int d = t * 4;

    const float* xb = x + (size_t)b * L * D + d;
    float* ob = out + (size_t)b * L * D + d;

    __shared__ float s_red[2][R][NW];

    float nwv[4], wv[4][4];
    load4(nw + d, nwv);
    #pragma unroll
    for (int k = 0; k < 4; ++k) load4(cw + k * D + d, wv[k]);  // (K,1,D)

    // ---- Halo: rows l0-3 .. l0-1, batched: 3 reduces, ONE barrier ----
    float win[3][4];
    {
        float hx[3][4];
        #pragma unroll
        for (int j = 0; j < 3; ++j) {
            const int l = l0 - 3 + j;
            hx[j][0] = hx[j][1] = hx[j][2] = hx[j][3] = 0.0f;
            if (l >= 0) load4(xb + (size_t)l * D, hx[j]);
            float s = hx[j][0]*hx[j][0] + hx[j][1]*hx[j][1]
                    + hx[j][2]*hx[j][2] + hx[j][3]*hx[j][3];
            #pragma unroll
            for (int off = 32; off > 0; off >>= 1)
                s += __shfl_down(s, off, 64);
            if (lane == 0) s_red[0][j][wave] = s;
        }
        light_barrier();
        #pragma unroll
        for (int j = 0; j < 3; ++j) {
            float tot = 0.0f;
            #pragma unroll
            for (int w = 0; w < NW; ++w) tot += s_red[0][j][w];
            float irms = rsqrtf(tot * (1.0f / D) + EPS);
            #pragma unroll
            for (int i = 0; i < 4; ++i) win[j][i] = hx[j][i] * irms * nwv[i];
        }
    }

    // ---- Main: NG groups of R rows, one light barrier per group ----
    float cur[R][4], nxt[R][4];
    #pragma unroll
    for (int r = 0; r < R; ++r)
        load4(xb + (size_t)(l0 + r) * D, cur[r]);

    #pragma unroll
    for (int g = 0; g < NG; ++g) {
        const int par = (g + 1) & 1;    // halo used buffer 0

        // 4 independent reduce chains
        #pragma unroll
        for (int r = 0; r < R; ++r) {
            float s = cur[r][0]*cur[r][0] + cur[r][1]*cur[r][1]
                    + cur[r][2]*cur[r][2] + cur[r][3]*cur[r][3];
            #pragma unroll
            for (int off = 32; off > 0; off >>= 1)
                s += __shfl_down(s, off, 64);
            if (lane == 0) s_red[par][r][wave] = s;
        }

        // prefetch next group's rows; loads stay in flight across the barrier
        if (g + 1 < NG) {
            #pragma unroll
            for (int r = 0; r < R; ++r)
                load4(xb + (size_t)(l0 + (g + 1) * R + r) * D, nxt[r]);
        }

        light_barrier();

        #pragma unroll
        for (int r = 0; r < R; ++r) {
            float tot = 0.0f;
            #pragma unroll
            for (int w = 0; w < NW; ++w) tot += s_red[par][r][w];
            const float irms = rsqrtf(tot * (1.0f / D) + EPS);

            float c[4], y[4];
            #pragma unroll
            for (int i = 0; i < 4; ++i) {
                c[i] = cur[r][i] * irms * nwv[i];
                y[i] = wv[0][i]*win[0][i] + wv[1][i]*win[1][i]
                     + wv[2][i]*win[2][i] + wv[3][i]*c[i];
                y[i] = y[i] / (1.0f + __expf(-y[i]));   // SiLU
            }
            floatx4 o;
            o.x = y[0]; o.y = y[1]; o.z = y[2]; o.w = y[3];
            __builtin_nontemporal_store(o,
                reinterpret_cast<floatx4*>(ob + (size_t)(l0 + g * R + r) * D));

            #pragma unroll
            for (int i = 0; i < 4; ++i) {
                win[0][i] = win[1][i];
                win[1][i] = win[2][i];
                win[2][i] = c[i];
            }
        }

        #pragma unroll
        for (int r = 0; r < R; ++r)
            #pragma unroll
            for (int i = 0; i < 4; ++i) cur[r][i] = nxt[r][i];
    }
}

extern "C" void kernel_launch(void* const* d_in, const int* in_sizes, int n_in,
                              void* d_out, int out_size, void* d_ws, size_t ws_size,
                              hipStream_t stream) {
    const float* x  = (const float*)d_in[0];   // (B, L, D) fp32
    const float* nw = (const float*)d_in[1];   // (D,) fp32
    const float* cw = (const float*)d_in[2];   // (K, 1, D) fp32
    float* out = (float*)d_out;                // (B, L, D) fp32

    fused_kernel<<<NWG, 512, 0, stream>>>(x, nw, cw, out);
}